// Round 2
// baseline (2241.157 us; speedup 1.0000x reference)
//
#include <hip/hip_runtime.h>
#include <math.h>

#define B_ 16
#define C_ 16
#define P_ 512
#define D_ 256

constexpr int HEADS = B_ * C_;     // 256
constexpr int PD    = P_ * D_;     // 131072
constexpr float QSCALE = 0.0625f;  // D^-0.5 = 1/16

// ---------------------------------------------------------------------------
// Kernel 1: S[b,p,d] = sum_c aw[c,p,d] * query[b,c,p,d]   (float4 over d)
// ---------------------------------------------------------------------------
__global__ __launch_bounds__(256) void k_sum_acw(const float* __restrict__ query,
                                                 const float* __restrict__ aw,
                                                 float* __restrict__ S) {
    int idx = blockIdx.x * 256 + threadIdx.x;       // float4 index over B*P*D/4
    int e = idx * 4;
    int d = e % D_;
    int p = (e / D_) % P_;
    int b = e / (D_ * P_);
    const float4* q4 = reinterpret_cast<const float4*>(query);
    const float4* a4 = reinterpret_cast<const float4*>(aw);
    int qbase = (((b * C_) * P_ + p) * D_ + d) >> 2;
    int abase = (p * D_ + d) >> 2;
    float4 acc = {0.f, 0.f, 0.f, 0.f};
#pragma unroll
    for (int c = 0; c < C_; ++c) {
        float4 qv = q4[qbase + c * (PD / 4)];
        float4 av = a4[abase + c * (PD / 4)];
        acc.x += qv.x * av.x;
        acc.y += qv.y * av.y;
        acc.z += qv.z * av.z;
        acc.w += qv.w * av.w;
    }
    reinterpret_cast<float4*>(S)[idx] = acc;
}

// ---------------------------------------------------------------------------
// Kernel 2: fused q/k/v projection for heads [head0, head0+gridDim.z).
//   Scratch Q/K/V are indexed by chunk-local head; inputs by global head.
// ---------------------------------------------------------------------------
__global__ __launch_bounds__(256) void k_proj(
    const float* __restrict__ query, const float* __restrict__ aw,
    const float* __restrict__ S,
    const float* __restrict__ Wq, const float* __restrict__ Wk,
    const float* __restrict__ Wv,
    const float* __restrict__ bq, const float* __restrict__ bk,
    const float* __restrict__ bv,
    float* __restrict__ Q, float* __restrict__ K, float* __restrict__ V,
    int head0) {
    constexpr int LD = 68;
    __shared__ float Aq[32][LD];  // transposed: [k][m]
    __shared__ float Ac[32][LD];
    __shared__ float Bq[32][LD];  // [k][n]
    __shared__ float Bk[32][LD];
    __shared__ float Bv[32][LD];

    int tid = threadIdx.x;
    int n0 = blockIdx.x * 64;
    int m0 = blockIdx.y * 64;
    int lh = blockIdx.z;            // chunk-local head
    int hd = head0 + lh;            // global head
    int b = hd / C_, c = hd % C_;
    int tx = tid & 15, ty = tid >> 4;

    float accq[4][4] = {}, acck[4][4] = {}, accv[4][4] = {};

    for (int kk = 0; kk < D_; kk += 32) {
#pragma unroll
        for (int i = 0; i < 8; ++i) {   // A tiles: 64 rows x 32 cols, transposed store
            int l = tid + i * 256;
            int col = l & 31, row = l >> 5;
            int p = m0 + row, d = kk + col;
            float qv = query[(size_t)(hd * P_ + p) * D_ + d];
            float sv = S[(size_t)(b * P_ + p) * D_ + d];
            float av = aw[(size_t)(c * P_ + p) * D_ + d];
            Aq[col][row] = qv;
            Ac[col][row] = sv - av * qv;
        }
#pragma unroll
        for (int i = 0; i < 8; ++i) {   // B tiles: 32 rows(k) x 64 cols(n)
            int l = tid + i * 256;
            int col = l & 63, row = l >> 6;
            int widx = (c * D_ + kk + row) * D_ + n0 + col;
            Bq[row][col] = Wq[widx];
            Bk[row][col] = Wk[widx];
            Bv[row][col] = Wv[widx];
        }
        __syncthreads();
#pragma unroll
        for (int kkk = 0; kkk < 32; ++kkk) {
            float4 a1 = *reinterpret_cast<const float4*>(&Aq[kkk][ty * 4]);
            float4 a2 = *reinterpret_cast<const float4*>(&Ac[kkk][ty * 4]);
            float4 w1 = *reinterpret_cast<const float4*>(&Bq[kkk][tx * 4]);
            float4 w2 = *reinterpret_cast<const float4*>(&Bk[kkk][tx * 4]);
            float4 w3 = *reinterpret_cast<const float4*>(&Bv[kkk][tx * 4]);
            float av1[4] = {a1.x, a1.y, a1.z, a1.w};
            float av2[4] = {a2.x, a2.y, a2.z, a2.w};
            float bw1[4] = {w1.x, w1.y, w1.z, w1.w};
            float bw2[4] = {w2.x, w2.y, w2.z, w2.w};
            float bw3[4] = {w3.x, w3.y, w3.z, w3.w};
#pragma unroll
            for (int i = 0; i < 4; ++i)
#pragma unroll
                for (int j = 0; j < 4; ++j) {
                    accq[i][j] += av1[i] * bw1[j];
                    acck[i][j] += av2[i] * bw2[j];
                    accv[i][j] += av2[i] * bw3[j];
                }
        }
        __syncthreads();
    }

    int ecol = n0 + tx * 4;
    float4 q_b = *reinterpret_cast<const float4*>(&bq[c * D_ + ecol]);
    float4 k_b = *reinterpret_cast<const float4*>(&bk[c * D_ + ecol]);
    float4 v_b = *reinterpret_cast<const float4*>(&bv[c * D_ + ecol]);
    float qba[4] = {q_b.x, q_b.y, q_b.z, q_b.w};
    float kba[4] = {k_b.x, k_b.y, k_b.z, k_b.w};
    float vba[4] = {v_b.x, v_b.y, v_b.z, v_b.w};

#pragma unroll
    for (int i = 0; i < 4; ++i) {
        int p = m0 + ty * 4 + i;
        size_t obase = (size_t)(lh * P_ + p) * D_ + ecol;   // chunk-local
        float4 oq, ok, ov;
        float* oqp = &oq.x; float* okp = &ok.x; float* ovp = &ov.x;
#pragma unroll
        for (int j = 0; j < 4; ++j) {
            oqp[j] = fmaxf(accq[i][j] + qba[j], 0.f) * QSCALE;
            okp[j] = fmaxf(acck[i][j] + kba[j], 0.f);
            ovp[j] = fmaxf(accv[i][j] + vba[j], 0.f);
        }
        *reinterpret_cast<float4*>(&Q[obase]) = oq;
        *reinterpret_cast<float4*>(&K[obase]) = ok;
        *reinterpret_cast<float4*>(&V[obase]) = ov;
    }
}

// ---------------------------------------------------------------------------
// Kernel 3a: scores = Q @ K^T per chunk-local head. M=N=512, K=256.
// ---------------------------------------------------------------------------
__global__ __launch_bounds__(256) void k_scores(const float* __restrict__ Q,
                                                const float* __restrict__ K,
                                                float* __restrict__ Sc) {
    constexpr int LD = 68;
    __shared__ float At[32][LD];
    __shared__ float Bt[32][LD];
    int tid = threadIdx.x;
    int n0 = blockIdx.x * 64;
    int m0 = blockIdx.y * 64;
    int lh = blockIdx.z;
    int tx = tid & 15, ty = tid >> 4;
    float acc[4][4] = {};
    for (int kk = 0; kk < D_; kk += 32) {
#pragma unroll
        for (int i = 0; i < 8; ++i) {
            int l = tid + i * 256;
            int col = l & 31, row = l >> 5;
            At[col][row] = Q[(size_t)(lh * P_ + m0 + row) * D_ + kk + col];
            Bt[col][row] = K[(size_t)(lh * P_ + n0 + row) * D_ + kk + col];
        }
        __syncthreads();
#pragma unroll
        for (int kkk = 0; kkk < 32; ++kkk) {
            float4 a = *reinterpret_cast<const float4*>(&At[kkk][ty * 4]);
            float4 w = *reinterpret_cast<const float4*>(&Bt[kkk][tx * 4]);
            float av[4] = {a.x, a.y, a.z, a.w};
            float bv[4] = {w.x, w.y, w.z, w.w};
#pragma unroll
            for (int i = 0; i < 4; ++i)
#pragma unroll
                for (int j = 0; j < 4; ++j) acc[i][j] += av[i] * bv[j];
        }
        __syncthreads();
    }
#pragma unroll
    for (int i = 0; i < 4; ++i) {
        size_t obase = (size_t)lh * P_ * P_ + (size_t)(m0 + ty * 4 + i) * P_ + n0 + tx * 4;
        float4 o = {acc[i][0], acc[i][1], acc[i][2], acc[i][3]};
        *reinterpret_cast<float4*>(&Sc[obase]) = o;
    }
}

// ---------------------------------------------------------------------------
// Kernel 3b: in-place row softmax over last dim (512). One block per row.
// ---------------------------------------------------------------------------
__global__ __launch_bounds__(256) void k_softmax(float* __restrict__ Sc) {
    __shared__ float red[4];
    size_t row = blockIdx.x;
    int tid = threadIdx.x;
    float* r = Sc + row * P_;
    float v0 = r[tid], v1 = r[tid + 256];
    int lane = tid & 63, wid = tid >> 6;

    float m = fmaxf(v0, v1);
#pragma unroll
    for (int off = 32; off; off >>= 1) m = fmaxf(m, __shfl_xor(m, off));
    if (lane == 0) red[wid] = m;
    __syncthreads();
    m = fmaxf(fmaxf(red[0], red[1]), fmaxf(red[2], red[3]));
    __syncthreads();

    float e0 = __expf(v0 - m), e1 = __expf(v1 - m);
    float s = e0 + e1;
#pragma unroll
    for (int off = 32; off; off >>= 1) s += __shfl_xor(s, off);
    if (lane == 0) red[wid] = s;
    __syncthreads();
    s = red[0] + red[1] + red[2] + red[3];
    float inv = 1.0f / s;
    r[tid] = e0 * inv;
    r[tid + 256] = e1 * inv;
}

// ---------------------------------------------------------------------------
// Kernel 3c: out = attn @ V. Scratch (A=Sc, V) chunk-local; out global head.
// ---------------------------------------------------------------------------
__global__ __launch_bounds__(256) void k_out(const float* __restrict__ A,
                                             const float* __restrict__ V,
                                             float* __restrict__ O, int head0) {
    constexpr int LD = 68;
    __shared__ float At[32][LD];  // [k(q)][m(p)]
    __shared__ float Bs[32][LD];  // [k(q)][n(e)]
    int tid = threadIdx.x;
    int n0 = blockIdx.x * 64;
    int m0 = blockIdx.y * 64;
    int lh = blockIdx.z;
    int hd = head0 + lh;
    int tx = tid & 15, ty = tid >> 4;
    float acc[4][4] = {};
    for (int kk = 0; kk < P_; kk += 32) {
#pragma unroll
        for (int i = 0; i < 8; ++i) {
            int l = tid + i * 256;
            int col = l & 31, row = l >> 5;
            At[col][row] = A[(size_t)lh * P_ * P_ + (size_t)(m0 + row) * P_ + kk + col];
        }
#pragma unroll
        for (int i = 0; i < 8; ++i) {
            int l = tid + i * 256;
            int col = l & 63, row = l >> 6;
            Bs[row][col] = V[(size_t)(lh * P_ + kk + row) * D_ + n0 + col];
        }
        __syncthreads();
#pragma unroll
        for (int kkk = 0; kkk < 32; ++kkk) {
            float4 a = *reinterpret_cast<const float4*>(&At[kkk][ty * 4]);
            float4 w = *reinterpret_cast<const float4*>(&Bs[kkk][tx * 4]);
            float av[4] = {a.x, a.y, a.z, a.w};
            float bv[4] = {w.x, w.y, w.z, w.w};
#pragma unroll
            for (int i = 0; i < 4; ++i)
#pragma unroll
                for (int j = 0; j < 4; ++j) acc[i][j] += av[i] * bv[j];
        }
        __syncthreads();
    }
#pragma unroll
    for (int i = 0; i < 4; ++i) {
        size_t obase = (size_t)(hd * P_ + m0 + ty * 4 + i) * D_ + n0 + tx * 4;
        float4 o = {acc[i][0], acc[i][1], acc[i][2], acc[i][3]};
        *reinterpret_cast<float4*>(&O[obase]) = o;
    }
}

// ---------------------------------------------------------------------------
extern "C" void kernel_launch(void* const* d_in, const int* in_sizes, int n_in,
                              void* d_out, int out_size, void* d_ws, size_t ws_size,
                              hipStream_t stream) {
    (void)in_sizes; (void)n_in; (void)out_size;
    const float* query = (const float*)d_in[0];
    const float* aw    = (const float*)d_in[1];
    const float* Wq    = (const float*)d_in[2];
    const float* Wk    = (const float*)d_in[3];
    const float* Wv    = (const float*)d_in[4];
    const float* bq    = (const float*)d_in[5];
    const float* bk    = (const float*)d_in[6];
    const float* bv    = (const float*)d_in[7];
    float* out = (float*)d_out;

    // Adaptive head-chunked scratch layout:
    //   S       : B*P*D floats        = 8 MiB   (resident)
    //   per head: Q,K,V = 3*P*D floats (1.5 MiB) + Sc = P*P floats (1 MiB)
    const size_t s_elems = (size_t)B_ * P_ * D_;          // 2M floats
    const size_t qkv_per_head = (size_t)3 * P_ * D_;      // 384K floats
    const size_t sc_per_head  = (size_t)P_ * P_;          // 256K floats
    const size_t per_head_bytes = (qkv_per_head + sc_per_head) * 4;  // 2.5 MiB
    size_t avail = ws_size > s_elems * 4 ? ws_size - s_elems * 4 : 0;
    int H = (int)(avail / per_head_bytes);
    if (H < 1) H = 1;
    if (H > HEADS) H = HEADS;

    float* S  = (float*)d_ws;
    float* Q  = S + s_elems;
    float* K  = Q + (size_t)H * P_ * D_;
    float* V  = K + (size_t)H * P_ * D_;
    float* Sc = V + (size_t)H * P_ * D_;

    k_sum_acw<<<(B_ * P_ * D_ / 4) / 256, 256, 0, stream>>>(query, aw, S);

    for (int head0 = 0; head0 < HEADS; head0 += H) {
        int Hc = HEADS - head0 < H ? HEADS - head0 : H;
        k_proj<<<dim3(D_ / 64, P_ / 64, Hc), 256, 0, stream>>>(
            query, aw, S, Wq, Wk, Wv, bq, bk, bv, Q, K, V, head0);
        k_scores<<<dim3(P_ / 64, P_ / 64, Hc), 256, 0, stream>>>(Q, K, Sc);
        k_softmax<<<Hc * P_, 256, 0, stream>>>(Sc);
        k_out<<<dim3(D_ / 64, P_ / 64, Hc), 256, 0, stream>>>(Sc, V, out, head0);
    }
}

// Round 4
// 1161.642 us; speedup vs baseline: 1.9293x; 1.9293x over previous
//
#include <hip/hip_runtime.h>
#include <math.h>

#define B_ 16
#define C_ 16
#define P_ 512
#define D_ 256

constexpr int HEADS = B_ * C_;     // 256
constexpr int PD    = P_ * D_;
constexpr float QSCALE = 0.0625f;  // D^-0.5

typedef __attribute__((ext_vector_type(8))) short short8;   // 8 bf16
typedef __attribute__((ext_vector_type(4))) short short4_t; // 4 bf16
typedef __attribute__((ext_vector_type(4))) float floatx4;  // MFMA acc

#define MFMA_BF16 __builtin_amdgcn_mfma_f32_16x16x32_bf16

// fp32 -> (hi bf16, lo bf16) with x ~= hi + lo (residual ~2^-17 rel)
__device__ inline short2 split_hl(float x) {
    unsigned xb = __float_as_uint(x);
    unsigned hb = (xb + 0x8000u) & 0xFFFF0000u;
    float lf = x - __uint_as_float(hb);
    short2 r;
    r.x = (short)(hb >> 16);
    r.y = (short)((__float_as_uint(lf) + 0x8000u) >> 16);
    return r;
}
__device__ inline unsigned packsplit(float x) {
    short2 s = split_hl(x);
    return (unsigned)(unsigned short)s.x | ((unsigned)(unsigned short)s.y << 16);
}

// ---------------------------------------------------------------------------
// S[b,p,d] = sum_c aw[c,p,d] * query[b,c,p,d]
// ---------------------------------------------------------------------------
__global__ __launch_bounds__(256) void k_sum_acw(const float* __restrict__ query,
                                                 const float* __restrict__ aw,
                                                 float* __restrict__ S) {
    int idx = blockIdx.x * 256 + threadIdx.x;
    int e = idx * 4;
    int d = e % D_;
    int p = (e / D_) % P_;
    int b = e / (D_ * P_);
    const float4* q4 = reinterpret_cast<const float4*>(query);
    const float4* a4 = reinterpret_cast<const float4*>(aw);
    int qbase = (((b * C_) * P_ + p) * D_ + d) >> 2;
    int abase = (p * D_ + d) >> 2;
    float4 acc = {0.f, 0.f, 0.f, 0.f};
#pragma unroll
    for (int c = 0; c < C_; ++c) {
        float4 qv = q4[qbase + c * (PD / 4)];
        float4 av = a4[abase + c * (PD / 4)];
        acc.x += qv.x * av.x;
        acc.y += qv.y * av.y;
        acc.z += qv.z * av.z;
        acc.w += qv.w * av.w;
    }
    reinterpret_cast<float4*>(S)[idx] = acc;
}

// ---------------------------------------------------------------------------
// Pack + transpose weights: W2t[wsel][c][n][k] pair-words from W[c][k][n] fp32
// ---------------------------------------------------------------------------
__global__ __launch_bounds__(256) void k_wpack(const float* __restrict__ Wq,
                                               const float* __restrict__ Wk,
                                               const float* __restrict__ Wv,
                                               unsigned* __restrict__ W2t) {
    __shared__ float tile[64][68];
    int wsel = blockIdx.z / C_;
    int c    = blockIdx.z % C_;
    int k0 = blockIdx.x * 64, n0 = blockIdx.y * 64;
    const float* Wsrc = wsel == 0 ? Wq : (wsel == 1 ? Wk : Wv);
    int tid = threadIdx.x;
#pragma unroll
    for (int it = 0; it < 4; ++it) {
        int idx = tid + it * 256;
        int kr = idx >> 4, nc = (idx & 15) * 4;
        float4 f = *reinterpret_cast<const float4*>(
            &Wsrc[(size_t)(c * D_ + k0 + kr) * D_ + n0 + nc]);
        *reinterpret_cast<float4*>(&tile[kr][nc]) = f;
    }
    __syncthreads();
#pragma unroll
    for (int it = 0; it < 4; ++it) {
        int idx = tid + it * 256;
        int nr = idx >> 4, kc = (idx & 15) * 4;
        uint4 u;
        u.x = packsplit(tile[kc + 0][nr]);
        u.y = packsplit(tile[kc + 1][nr]);
        u.z = packsplit(tile[kc + 2][nr]);
        u.w = packsplit(tile[kc + 3][nr]);
        *reinterpret_cast<uint4*>(
            &W2t[((size_t)(wsel * C_ + c) * D_ + n0 + nr) * D_ + k0 + kc]) = u;
    }
}

// ---------------------------------------------------------------------------
// Fused split-bf16 MFMA projection. blockIdx.z = lh*3 + oid (0=q,1=k,2=v).
// Writes Q2/K2 as [p][e] pair-words; V as V2t [e][p] pair-words (transposed).
// ---------------------------------------------------------------------------
__global__ __launch_bounds__(256) void k_proj_mfma(
    const float* __restrict__ query, const float* __restrict__ aw,
    const float* __restrict__ S, const unsigned* __restrict__ W2t,
    const float* __restrict__ bq, const float* __restrict__ bk,
    const float* __restrict__ bv,
    unsigned* __restrict__ Q2, unsigned* __restrict__ K2,
    unsigned* __restrict__ V2t, int head0) {
    __shared__ short Ah[128 * 40], Al[128 * 40], Bh[128 * 40], Bl[128 * 40];
    int tid = threadIdx.x;
    int lane = tid & 63, wv = tid >> 6;
    int wm = wv >> 1, wn = wv & 1;
    int ln = lane & 15, q8 = (lane >> 4) * 8, quad4 = (lane >> 4) * 4;
    int n0 = blockIdx.x * 128;
    int m0 = blockIdx.y * 128;
    int lh = blockIdx.z / 3, oid = blockIdx.z % 3;
    int hd = head0 + lh;
    int b = hd / C_, c = hd % C_;
    const unsigned* Wt = W2t + (size_t)(oid * C_ + c) * D_ * D_;

    floatx4 acc[4][4] = {};

    for (int kk = 0; kk < D_; kk += 32) {
#pragma unroll
        for (int it = 0; it < 4; ++it) {   // A: 128 x 32 from fp32 (query/ctx)
            int idx = tid + it * 256;
            int row = idx >> 3, ck = (idx & 7) * 4;
            size_t g = (size_t)(hd * P_ + m0 + row) * D_ + kk + ck;
            float4 qv = *reinterpret_cast<const float4*>(&query[g]);
            float x0, x1, x2, x3;
            if (oid == 0) {
                x0 = qv.x; x1 = qv.y; x2 = qv.z; x3 = qv.w;
            } else {
                size_t gs = (size_t)(b * P_ + m0 + row) * D_ + kk + ck;
                size_t ga = (size_t)(c * P_ + m0 + row) * D_ + kk + ck;
                float4 sv = *reinterpret_cast<const float4*>(&S[gs]);
                float4 av = *reinterpret_cast<const float4*>(&aw[ga]);
                x0 = sv.x - av.x * qv.x; x1 = sv.y - av.y * qv.y;
                x2 = sv.z - av.z * qv.z; x3 = sv.w - av.w * qv.w;
            }
            short4_t h4, l4;
            short2 s0 = split_hl(x0), s1 = split_hl(x1);
            short2 s2 = split_hl(x2), s3 = split_hl(x3);
            h4[0] = s0.x; l4[0] = s0.y;
            h4[1] = s1.x; l4[1] = s1.y;
            h4[2] = s2.x; l4[2] = s2.y;
            h4[3] = s3.x; l4[3] = s3.y;
            *reinterpret_cast<short4_t*>(&Ah[row * 40 + ck]) = h4;
            *reinterpret_cast<short4_t*>(&Al[row * 40 + ck]) = l4;
        }
#pragma unroll
        for (int it = 0; it < 4; ++it) {   // B: 128 x 32 pair-words (W2t)
            int idx = tid + it * 256;
            int nr = idx >> 3, ck = (idx & 7) * 4;
            uint4 u = *reinterpret_cast<const uint4*>(
                &Wt[(size_t)(n0 + nr) * D_ + kk + ck]);
            short4_t h4, l4;
            h4[0] = (short)(u.x & 0xFFFF); l4[0] = (short)(u.x >> 16);
            h4[1] = (short)(u.y & 0xFFFF); l4[1] = (short)(u.y >> 16);
            h4[2] = (short)(u.z & 0xFFFF); l4[2] = (short)(u.z >> 16);
            h4[3] = (short)(u.w & 0xFFFF); l4[3] = (short)(u.w >> 16);
            *reinterpret_cast<short4_t*>(&Bh[nr * 40 + ck]) = h4;
            *reinterpret_cast<short4_t*>(&Bl[nr * 40 + ck]) = l4;
        }
        __syncthreads();
        short8 ah[4], al[4], bh[4], bl[4];
#pragma unroll
        for (int i = 0; i < 4; ++i) {
            ah[i] = *reinterpret_cast<const short8*>(&Ah[(wm * 64 + i * 16 + ln) * 40 + q8]);
            al[i] = *reinterpret_cast<const short8*>(&Al[(wm * 64 + i * 16 + ln) * 40 + q8]);
            bh[i] = *reinterpret_cast<const short8*>(&Bh[(wn * 64 + i * 16 + ln) * 40 + q8]);
            bl[i] = *reinterpret_cast<const short8*>(&Bl[(wn * 64 + i * 16 + ln) * 40 + q8]);
        }
#pragma unroll
        for (int i = 0; i < 4; ++i)
#pragma unroll
            for (int j = 0; j < 4; ++j) {
                acc[i][j] = MFMA_BF16(ah[i], bh[j], acc[i][j], 0, 0, 0);
                acc[i][j] = MFMA_BF16(ah[i], bl[j], acc[i][j], 0, 0, 0);
                acc[i][j] = MFMA_BF16(al[i], bh[j], acc[i][j], 0, 0, 0);
            }
        __syncthreads();
    }

    const float* bias = oid == 0 ? bq : (oid == 1 ? bk : bv);
    float scale = oid == 0 ? QSCALE : 1.0f;
#pragma unroll
    for (int j = 0; j < 4; ++j) {
        int n_g = n0 + wn * 64 + j * 16 + ln;
        float bb = bias[c * D_ + n_g];
#pragma unroll
        for (int i = 0; i < 4; ++i) {
            int p0 = m0 + wm * 64 + i * 16 + quad4;
            if (oid == 2) {
                uint4 u;
                u.x = packsplit(fmaxf(acc[i][j][0] + bb, 0.f));
                u.y = packsplit(fmaxf(acc[i][j][1] + bb, 0.f));
                u.z = packsplit(fmaxf(acc[i][j][2] + bb, 0.f));
                u.w = packsplit(fmaxf(acc[i][j][3] + bb, 0.f));
                *reinterpret_cast<uint4*>(&V2t[(size_t)(lh * D_ + n_g) * P_ + p0]) = u;
            } else {
                unsigned* dst = oid == 0 ? Q2 : K2;
#pragma unroll
                for (int r = 0; r < 4; ++r) {
                    float v = fmaxf(acc[i][j][r] + bb, 0.f) * scale;
                    dst[(size_t)(lh * P_ + p0 + r) * D_ + n_g] = packsplit(v);
                }
            }
        }
    }
}

// ---------------------------------------------------------------------------
// scores = Q @ K^T, fp32 out. M=N=512, K=256, per chunk-local head.
// ---------------------------------------------------------------------------
__global__ __launch_bounds__(256) void k_scores_mfma(
    const unsigned* __restrict__ Q2, const unsigned* __restrict__ K2,
    float* __restrict__ Sc) {
    __shared__ short Ah[128 * 40], Al[128 * 40], Bh[128 * 40], Bl[128 * 40];
    int tid = threadIdx.x;
    int lane = tid & 63, wv = tid >> 6;
    int wm = wv >> 1, wn = wv & 1;
    int ln = lane & 15, q8 = (lane >> 4) * 8, quad4 = (lane >> 4) * 4;
    int n0 = blockIdx.x * 128;
    int m0 = blockIdx.y * 128;
    int lh = blockIdx.z;

    floatx4 acc[4][4] = {};

    for (int kk = 0; kk < D_; kk += 32) {
#pragma unroll
        for (int it = 0; it < 4; ++it) {
            int idx = tid + it * 256;
            int row = idx >> 3, ck = (idx & 7) * 4;
            uint4 ua = *reinterpret_cast<const uint4*>(
                &Q2[(size_t)(lh * P_ + m0 + row) * D_ + kk + ck]);
            uint4 ub = *reinterpret_cast<const uint4*>(
                &K2[(size_t)(lh * P_ + n0 + row) * D_ + kk + ck]);
            short4_t h4, l4;
            h4[0] = (short)(ua.x & 0xFFFF); l4[0] = (short)(ua.x >> 16);
            h4[1] = (short)(ua.y & 0xFFFF); l4[1] = (short)(ua.y >> 16);
            h4[2] = (short)(ua.z & 0xFFFF); l4[2] = (short)(ua.z >> 16);
            h4[3] = (short)(ua.w & 0xFFFF); l4[3] = (short)(ua.w >> 16);
            *reinterpret_cast<short4_t*>(&Ah[row * 40 + ck]) = h4;
            *reinterpret_cast<short4_t*>(&Al[row * 40 + ck]) = l4;
            h4[0] = (short)(ub.x & 0xFFFF); l4[0] = (short)(ub.x >> 16);
            h4[1] = (short)(ub.y & 0xFFFF); l4[1] = (short)(ub.y >> 16);
            h4[2] = (short)(ub.z & 0xFFFF); l4[2] = (short)(ub.z >> 16);
            h4[3] = (short)(ub.w & 0xFFFF); l4[3] = (short)(ub.w >> 16);
            *reinterpret_cast<short4_t*>(&Bh[row * 40 + ck]) = h4;
            *reinterpret_cast<short4_t*>(&Bl[row * 40 + ck]) = l4;
        }
        __syncthreads();
        short8 ah[4], al[4], bh[4], bl[4];
#pragma unroll
        for (int i = 0; i < 4; ++i) {
            ah[i] = *reinterpret_cast<const short8*>(&Ah[(wm * 64 + i * 16 + ln) * 40 + q8]);
            al[i] = *reinterpret_cast<const short8*>(&Al[(wm * 64 + i * 16 + ln) * 40 + q8]);
            bh[i] = *reinterpret_cast<const short8*>(&Bh[(wn * 64 + i * 16 + ln) * 40 + q8]);
            bl[i] = *reinterpret_cast<const short8*>(&Bl[(wn * 64 + i * 16 + ln) * 40 + q8]);
        }
#pragma unroll
        for (int i = 0; i < 4; ++i)
#pragma unroll
            for (int j = 0; j < 4; ++j) {
                acc[i][j] = MFMA_BF16(ah[i], bh[j], acc[i][j], 0, 0, 0);
                acc[i][j] = MFMA_BF16(ah[i], bl[j], acc[i][j], 0, 0, 0);
                acc[i][j] = MFMA_BF16(al[i], bh[j], acc[i][j], 0, 0, 0);
            }
        __syncthreads();
    }
#pragma unroll
    for (int j = 0; j < 4; ++j) {
        int n_g = n0 + wn * 64 + j * 16 + ln;
#pragma unroll
        for (int i = 0; i < 4; ++i) {
            int p0 = m0 + wm * 64 + i * 16 + quad4;
#pragma unroll
            for (int r = 0; r < 4; ++r)
                Sc[(size_t)lh * P_ * P_ + (size_t)(p0 + r) * P_ + n_g] = acc[i][j][r];
        }
    }
}

// ---------------------------------------------------------------------------
// Row softmax over 512, in place: fp32 scores -> packed (hi,lo) attn words.
// ---------------------------------------------------------------------------
__global__ __launch_bounds__(256) void k_softmax_pack(float* __restrict__ Sc) {
    __shared__ float red[4];
    size_t row = blockIdx.x;
    int tid = threadIdx.x;
    float* r = Sc + row * P_;
    float v0 = r[tid], v1 = r[tid + 256];
    int lane = tid & 63, wid = tid >> 6;

    float m = fmaxf(v0, v1);
#pragma unroll
    for (int off = 32; off; off >>= 1) m = fmaxf(m, __shfl_xor(m, off));
    if (lane == 0) red[wid] = m;
    __syncthreads();
    m = fmaxf(fmaxf(red[0], red[1]), fmaxf(red[2], red[3]));
    __syncthreads();

    float e0 = __expf(v0 - m), e1 = __expf(v1 - m);
    float s = e0 + e1;
#pragma unroll
    for (int off = 32; off; off >>= 1) s += __shfl_xor(s, off);
    if (lane == 0) red[wid] = s;
    __syncthreads();
    s = red[0] + red[1] + red[2] + red[3];
    float inv = 1.0f / s;
    unsigned* w = reinterpret_cast<unsigned*>(r);
    w[tid] = packsplit(e0 * inv);
    w[tid + 256] = packsplit(e1 * inv);
}

// ---------------------------------------------------------------------------
// out = attn @ V. A = attn pairs [p][q], B = V2t pairs [e][q]. K=512.
// ---------------------------------------------------------------------------
__global__ __launch_bounds__(256) void k_out_mfma(
    const unsigned* __restrict__ A2, const unsigned* __restrict__ V2t,
    float* __restrict__ O, int head0) {
    __shared__ short Ah[128 * 40], Al[128 * 40], Bh[128 * 40], Bl[128 * 40];
    int tid = threadIdx.x;
    int lane = tid & 63, wv = tid >> 6;
    int wm = wv >> 1, wn = wv & 1;
    int ln = lane & 15, q8 = (lane >> 4) * 8, quad4 = (lane >> 4) * 4;
    int n0 = blockIdx.x * 128;
    int m0 = blockIdx.y * 128;
    int lh = blockIdx.z;
    int hd = head0 + lh;

    floatx4 acc[4][4] = {};

    for (int kk = 0; kk < P_; kk += 32) {
#pragma unroll
        for (int it = 0; it < 4; ++it) {
            int idx = tid + it * 256;
            int row = idx >> 3, ck = (idx & 7) * 4;
            uint4 ua = *reinterpret_cast<const uint4*>(
                &A2[(size_t)lh * P_ * P_ + (size_t)(m0 + row) * P_ + kk + ck]);
            uint4 ub = *reinterpret_cast<const uint4*>(
                &V2t[(size_t)(lh * D_ + n0 + row) * P_ + kk + ck]);
            short4_t h4, l4;
            h4[0] = (short)(ua.x & 0xFFFF); l4[0] = (short)(ua.x >> 16);
            h4[1] = (short)(ua.y & 0xFFFF); l4[1] = (short)(ua.y >> 16);
            h4[2] = (short)(ua.z & 0xFFFF); l4[2] = (short)(ua.z >> 16);
            h4[3] = (short)(ua.w & 0xFFFF); l4[3] = (short)(ua.w >> 16);
            *reinterpret_cast<short4_t*>(&Ah[row * 40 + ck]) = h4;
            *reinterpret_cast<short4_t*>(&Al[row * 40 + ck]) = l4;
            h4[0] = (short)(ub.x & 0xFFFF); l4[0] = (short)(ub.x >> 16);
            h4[1] = (short)(ub.y & 0xFFFF); l4[1] = (short)(ub.y >> 16);
            h4[2] = (short)(ub.z & 0xFFFF); l4[2] = (short)(ub.z >> 16);
            h4[3] = (short)(ub.w & 0xFFFF); l4[3] = (short)(ub.w >> 16);
            *reinterpret_cast<short4_t*>(&Bh[row * 40 + ck]) = h4;
            *reinterpret_cast<short4_t*>(&Bl[row * 40 + ck]) = l4;
        }
        __syncthreads();
        short8 ah[4], al[4], bh[4], bl[4];
#pragma unroll
        for (int i = 0; i < 4; ++i) {
            ah[i] = *reinterpret_cast<const short8*>(&Ah[(wm * 64 + i * 16 + ln) * 40 + q8]);
            al[i] = *reinterpret_cast<const short8*>(&Al[(wm * 64 + i * 16 + ln) * 40 + q8]);
            bh[i] = *reinterpret_cast<const short8*>(&Bh[(wn * 64 + i * 16 + ln) * 40 + q8]);
            bl[i] = *reinterpret_cast<const short8*>(&Bl[(wn * 64 + i * 16 + ln) * 40 + q8]);
        }
#pragma unroll
        for (int i = 0; i < 4; ++i)
#pragma unroll
            for (int j = 0; j < 4; ++j) {
                acc[i][j] = MFMA_BF16(ah[i], bh[j], acc[i][j], 0, 0, 0);
                acc[i][j] = MFMA_BF16(ah[i], bl[j], acc[i][j], 0, 0, 0);
                acc[i][j] = MFMA_BF16(al[i], bh[j], acc[i][j], 0, 0, 0);
            }
        __syncthreads();
    }
#pragma unroll
    for (int j = 0; j < 4; ++j) {
        int n_g = n0 + wn * 64 + j * 16 + ln;
#pragma unroll
        for (int i = 0; i < 4; ++i) {
            int p0 = m0 + wm * 64 + i * 16 + quad4;
#pragma unroll
            for (int r = 0; r < 4; ++r)
                O[(size_t)(hd * P_ + p0 + r) * D_ + n_g] = acc[i][j][r];
        }
    }
}

// ---------------------------------------------------------------------------
extern "C" void kernel_launch(void* const* d_in, const int* in_sizes, int n_in,
                              void* d_out, int out_size, void* d_ws, size_t ws_size,
                              hipStream_t stream) {
    (void)in_sizes; (void)n_in; (void)out_size;
    const float* query = (const float*)d_in[0];
    const float* aw    = (const float*)d_in[1];
    const float* Wq    = (const float*)d_in[2];
    const float* Wk    = (const float*)d_in[3];
    const float* Wv    = (const float*)d_in[4];
    const float* bq    = (const float*)d_in[5];
    const float* bk    = (const float*)d_in[6];
    const float* bv    = (const float*)d_in[7];
    float* out = (float*)d_out;

    // Resident: S (8 MiB fp32) + W2t (12 MiB pair-words).
    // Per head: Q2,K2,V2t (P*D words each) + Sc (P*P fp32 / pair-words) = 2.5 MiB.
    char* ws = (char*)d_ws;
    const size_t s_words   = (size_t)B_ * P_ * D_;
    const size_t w2t_words = (size_t)3 * C_ * D_ * D_;
    const size_t fixed_bytes = (s_words + w2t_words) * 4;
    const size_t per_head_bytes = ((size_t)3 * P_ * D_ + (size_t)P_ * P_) * 4;
    size_t avail = ws_size > fixed_bytes ? ws_size - fixed_bytes : 0;
    int H = (int)(avail / per_head_bytes);
    if (H < 1) H = 1;
    if (H > HEADS) H = HEADS;

    float*    S   = (float*)ws;
    unsigned* W2t = (unsigned*)(ws + s_words * 4);
    unsigned* Q2  = (unsigned*)(ws + fixed_bytes);
    unsigned* K2  = Q2 + (size_t)H * P_ * D_;
    unsigned* V2t = K2 + (size_t)H * P_ * D_;
    float*    Sc  = (float*)(V2t + (size_t)H * P_ * D_);

    k_sum_acw<<<(B_ * P_ * D_ / 4) / 256, 256, 0, stream>>>(query, aw, S);
    k_wpack<<<dim3(D_ / 64, D_ / 64, 3 * C_), 256, 0, stream>>>(Wq, Wk, Wv, W2t);

    for (int head0 = 0; head0 < HEADS; head0 += H) {
        int Hc = HEADS - head0 < H ? HEADS - head0 : H;
        k_proj_mfma<<<dim3(D_ / 128, P_ / 128, 3 * Hc), 256, 0, stream>>>(
            query, aw, S, W2t, bq, bk, bv, Q2, K2, V2t, head0);
        k_scores_mfma<<<dim3(P_ / 128, P_ / 128, Hc), 256, 0, stream>>>(Q2, K2, Sc);
        k_softmax_pack<<<Hc * P_, 256, 0, stream>>>(Sc);
        k_out_mfma<<<dim3(D_ / 128, P_ / 128, Hc), 256, 0, stream>>>(
            (const unsigned*)Sc, V2t, out, head0);
    }
}